// Round 1
// 395.225 us; speedup vs baseline: 1.0620x; 1.0620x over previous
//
#include <hip/hip_runtime.h>
#include <hip/hip_bf16.h>

typedef __attribute__((ext_vector_type(8))) short short8;
typedef __attribute__((ext_vector_type(4))) float f32x4;

#define XT_IMG_BYTES (66*66*256*2)       // 2,230,272 per sample
#define XT_TOTAL_BYTES (32LL*XT_IMG_BYTES) // 71,368,704
#define WM_ROW_BYTES (2304*2)            // 4608
#define WM_IMG_BYTES (256*WM_ROW_BYTES)  // 1,179,648

static __device__ __forceinline__ void async16(void* lds, const void* g) {
  __builtin_amdgcn_global_load_lds((const __attribute__((address_space(1))) void*)g,
                                   (__attribute__((address_space(3))) void*)lds, 16, 0, 0);
}
static __device__ __forceinline__ ushort f2bf(float f) {
  __hip_bfloat16 h = __float2bfloat16(f);
  return *reinterpret_cast<ushort*>(&h);
}

// ---------------- zero ONLY the pad border of xT (spread over 256 blocks) -------
__global__ __launch_bounds__(256) void k_zeroborder(uint4* __restrict__ xT4) {
  const int b = blockIdx.x >> 3;
  const int t = ((blockIdx.x & 7) << 8) | threadIdx.x;  // 0..2047
  const uint4 z = make_uint4(0u, 0u, 0u, 0u);
  uint4* base = xT4 + (size_t)b * (66 * 66 * 32);  // 32 uint4 per pixel
  uint4* r0  = base;
  uint4* r65 = base + (size_t)65 * 66 * 32;
  for (int i = t; i < 2112; i += 2048) { r0[i] = z; r65[i] = z; }  // rows 0 & 65
  {                                                               // cols 0 & 65
    int r = (t >> 5) + 1, c = t & 31;                             // r 1..64
    base[((size_t)r * 66 + 0)  * 32 + c] = z;
    base[((size_t)r * 66 + 65) * 32 + c] = z;
  }
}

// ---------------- x [b][c][h][w] fp32 -> xT [b][h+1][w+1][c] bf16 (interior) ----
__global__ __launch_bounds__(256) void k_xpose(const float* __restrict__ x,
                                               ushort* __restrict__ xT) {
  __shared__ float lds[64][65];
  const int bx = blockIdx.x;
  const int b  = bx >> 8;
  const int h  = (bx >> 2) & 63;
  const int c0 = (bx & 3) << 6;
  const int t  = threadIdx.x;
  const int tw = t & 63, tg = t >> 6;
  const float* xp = x + (size_t)(b * 256 + c0) * 4096 + h * 64 + tw;
#pragma unroll
  for (int j = 0; j < 16; ++j) {
    int il = j * 4 + tg;
    lds[il][tw] = xp[(size_t)il * 4096];
  }
  __syncthreads();
  const int q  = t & 7;    // channel octet within the 64-channel group
  const int w0 = t >> 3;   // 0..31
  ushort* op = xT + (size_t)b * (66 * 66 * 256) + ((size_t)(h + 1) * 66 + 1) * 256 + c0;
#pragma unroll
  for (int j = 0; j < 2; ++j) {
    const int wl = j * 32 + w0;
    short8 v;
#pragma unroll
    for (int k2 = 0; k2 < 8; ++k2) v[k2] = (short)f2bf(lds[8 * q + k2][wl]);
    *(short8*)(op + (size_t)wl * 256 + 8 * q) = v;  // 16B stores, 128B/8-lane seg
  }
}

// ------- modulate+demodulate weights: wmod[b][o][r*256+i] bf16 -------------------
__global__ __launch_bounds__(256) void k_modw(const float* __restrict__ W,
                                              const float* __restrict__ y,
                                              ushort* __restrict__ wmod) {
  __shared__ float red[256];
  const int b = blockIdx.x >> 8, o = blockIdx.x & 255, t = threadIdx.x;
  const float* wp = W + (size_t)(o * 256 + t) * 9;
  float wr[9];
#pragma unroll
  for (int r = 0; r < 9; ++r) wr[r] = wp[r];
  const float ym = y[b * 256 + t] + 1.0f;
  float ss = 0.f;
#pragma unroll
  for (int r = 0; r < 9; ++r) ss += wr[r] * wr[r];
  red[t] = ss * ym * ym;
  __syncthreads();
  for (int s = 128; s > 0; s >>= 1) {
    if (t < s) red[t] += red[t + s];
    __syncthreads();
  }
  const float sc = rsqrtf(red[0] + 1e-8f) * ym;
  ushort* op = wmod + (size_t)(b * 256 + o) * 2304 + t;
#pragma unroll
  for (int r = 0; r < 9; ++r) op[r * 256] = f2bf(wr[r] * sc);
}

// ---------------- implicit-GEMM conv, 256x256 tile, BK=64, 8 waves --------------
// Pipelined: STAGE(kt+1) issued before counted s_waitcnt vmcnt(8) -> next tile's
// 8 loads stay in flight across raw s_barrier (no compiler vmcnt(0) drain).
// LDS rows (128B) XOR-swizzled at 16B-granule level: granule ^= (row&7), realized
// as linear LDS dest + pre-swizzled per-lane GLOBAL source (global_load_lds rule).
__global__ __launch_bounds__(512, 2) void k_gemm(const ushort* __restrict__ wmod,
                                                 const ushort* __restrict__ xT,
                                                 const float* __restrict__ bias,
                                                 float* __restrict__ out) {
  __shared__ ushort ldsA[2][16384];  // [buf][row o 0..255][k 0..63] (swizzled)
  __shared__ ushort ldsB[2][16384];  // [buf][pixel 0..255][k 0..63] (swizzled)

  const int t  = threadIdx.x;
  const int bx = blockIdx.x;
  const int xcd = bx & 7;                   // hw round-robins blocks over XCDs
  const int idx = bx >> 3;                  // 0..63
  const int b   = xcd + ((idx >> 4) << 3);  // 4 samples per XCD
  const int tn  = idx & 15;                 // N-tile: 4 image rows
  const int n0  = tn << 8;
  const int h0  = tn << 2;

  const int ln = t & 15;          // lane&15 -> A-row / B-col within fragment
  const int kq = (t >> 4) & 3;    // lane>>4 -> k-granule
  const int wv = t >> 6;
  const int wm = wv >> 2;         // 0..1  (128 output rows each)
  const int wn = wv & 3;          // 0..3  (64 output cols each)

  const char* wmodB = (const char*)wmod + (size_t)b * WM_IMG_BYTES;
  const char* xTB   = (const char*)xT   + (size_t)b * XT_IMG_BYTES;

  // per-thread staging source offsets (bytes), granule pre-swizzled g^(row&7)
  int gAoff[4], gBoff[4];
#pragma unroll
  for (int j = 0; j < 4; ++j) {
    const int s = j * 512 + t;          // slot 0..2047
    const int row = s >> 3, g = s & 7;
    gAoff[j] = row * WM_ROW_BYTES + ((g ^ (row & 7)) << 4);
    const int hr = row >> 6, wc = row & 63;  // B: row == pixel index
    gBoff[j] = ((h0 + hr) * 66 + wc) * 512 + ((g ^ (row & 7)) << 4);
  }

  // LDS read bases (ushort units); row&7 == ln&7 for every fragment row
  const int swz = ln & 7;
  const int g0 = ((0 | kq) ^ swz) << 3;   // kk=0 granule -> ushort offset
  const int g1 = ((4 | kq) ^ swz) << 3;   // kk=1
  const int aBase = (wm * 128 + ln) * 64;
  const int bBase = (wn * 64  + ln) * 64;

  f32x4 acc[8][4];
  const f32x4 z4 = {0.f, 0.f, 0.f, 0.f};
#pragma unroll
  for (int i = 0; i < 8; ++i)
#pragma unroll
    for (int j = 0; j < 4; ++j) acc[i][j] = z4;

#define STAGE(KT, BUF) do {                                              \
    const int r_  = (KT) >> 2;                                           \
    const int c2_ = ((KT) & 3) << 7;   /* 64-ch step in bytes */         \
    const int kh_ = r_ / 3;                                              \
    const int kw_ = r_ - kh_ * 3;                                        \
    const int koA_ = r_ * 512 + c2_;                                     \
    const int koB_ = (kh_ * 66 + kw_) * 512 + c2_;                       \
    ushort* la_ = &ldsA[BUF][0];                                         \
    ushort* lb_ = &ldsB[BUF][0];                                         \
    async16(la_ + (0 * 512 + t) * 8, wmodB + gAoff[0] + koA_);           \
    async16(lb_ + (0 * 512 + t) * 8, xTB   + gBoff[0] + koB_);           \
    async16(la_ + (1 * 512 + t) * 8, wmodB + gAoff[1] + koA_);           \
    async16(lb_ + (1 * 512 + t) * 8, xTB   + gBoff[1] + koB_);           \
    async16(la_ + (2 * 512 + t) * 8, wmodB + gAoff[2] + koA_);           \
    async16(lb_ + (2 * 512 + t) * 8, xTB   + gBoff[2] + koB_);           \
    async16(la_ + (3 * 512 + t) * 8, wmodB + gAoff[3] + koA_);           \
    async16(lb_ + (3 * 512 + t) * 8, xTB   + gBoff[3] + koB_);           \
  } while (0)

#define MF(F, E, A, B) acc[F][E] = __builtin_amdgcn_mfma_f32_16x16x32_bf16(A, B, acc[F][E], 0, 0, 0)

#define KHALF(GOFF) do {                                                 \
    const ushort* qa = bufA + aBase + (GOFF);                            \
    const ushort* qb = bufB + bBase + (GOFF);                            \
    short8 b0 = *(const short8*)(qb);                                    \
    short8 b1 = *(const short8*)(qb + 1024);                             \
    short8 b2 = *(const short8*)(qb + 2048);                             \
    short8 b3 = *(const short8*)(qb + 3072);                             \
    short8 a0 = *(const short8*)(qa);                                    \
    short8 a1 = *(const short8*)(qa + 1024);                             \
    short8 a2 = *(const short8*)(qa + 2048);                             \
    short8 a3 = *(const short8*)(qa + 3072);                             \
    short8 a4 = *(const short8*)(qa + 4096);                             \
    short8 a5 = *(const short8*)(qa + 5120);                             \
    short8 a6 = *(const short8*)(qa + 6144);                             \
    short8 a7 = *(const short8*)(qa + 7168);                             \
    __builtin_amdgcn_s_setprio(1);                                       \
    MF(0,0,a0,b0); MF(1,0,a1,b0); MF(2,0,a2,b0); MF(3,0,a3,b0);          \
    MF(4,0,a4,b0); MF(5,0,a5,b0); MF(6,0,a6,b0); MF(7,0,a7,b0);          \
    MF(0,1,a0,b1); MF(1,1,a1,b1); MF(2,1,a2,b1); MF(3,1,a3,b1);          \
    MF(4,1,a4,b1); MF(5,1,a5,b1); MF(6,1,a6,b1); MF(7,1,a7,b1);          \
    MF(0,2,a0,b2); MF(1,2,a1,b2); MF(2,2,a2,b2); MF(3,2,a3,b2);          \
    MF(4,2,a4,b2); MF(5,2,a5,b2); MF(6,2,a6,b2); MF(7,2,a7,b2);          \
    MF(0,3,a0,b3); MF(1,3,a1,b3); MF(2,3,a2,b3); MF(3,3,a3,b3);          \
    MF(4,3,a4,b3); MF(5,3,a5,b3); MF(6,3,a6,b3); MF(7,3,a7,b3);          \
    __builtin_amdgcn_s_setprio(0);                                       \
  } while (0)

  STAGE(0, 0);
  int cur = 0;
#pragma unroll 1
  for (int kt = 0; kt < 36; ++kt) {
    if (kt < 35) {
      STAGE(kt + 1, cur ^ 1);
      asm volatile("s_waitcnt vmcnt(8)" ::: "memory");  // kt's 8 landed; kt+1's ride
    } else {
      asm volatile("s_waitcnt vmcnt(0)" ::: "memory");
    }
    __builtin_amdgcn_s_barrier();            // (a) all waves' kt data visible
    __builtin_amdgcn_sched_barrier(0);
    {
      const ushort* bufA = &ldsA[cur][0];
      const ushort* bufB = &ldsB[cur][0];
      KHALF(g0);   // k = 0..31 of this 64-ch step
      KHALF(g1);   // k = 32..63
    }
    __builtin_amdgcn_sched_barrier(0);
    __builtin_amdgcn_s_barrier();            // (b) reads done before re-stage
    cur ^= 1;
  }

  // epilogue: C row = o (row=(lane>>4)*4+reg), col = n (lane&15)
  const float* bp = bias + wm * 128;
  float* outB = out + ((size_t)(b * 256 + wm * 128)) * 4096 + n0 + wn * 64 + ln;
#pragma unroll
  for (int mi = 0; mi < 8; ++mi) {
#pragma unroll
    for (int rg = 0; rg < 4; ++rg) {
      const int orow = mi * 16 + kq * 4 + rg;
      const float bv = bp[orow];
      float* po = outB + (size_t)orow * 4096;
#pragma unroll
      for (int ni = 0; ni < 4; ++ni) po[ni * 16] = acc[mi][ni][rg] + bv;
    }
  }
#undef STAGE
#undef MF
#undef KHALF
}

extern "C" void kernel_launch(void* const* d_in, const int* in_sizes, int n_in,
                              void* d_out, int out_size, void* d_ws, size_t ws_size,
                              hipStream_t stream) {
  const float* x    = (const float*)d_in[0];   // [32,256,64,64]
  const float* y    = (const float*)d_in[1];   // [32,256]
  const float* W    = (const float*)d_in[2];   // [256,256,3,3]
  const float* bias = (const float*)d_in[3];   // [256]
  float* out = (float*)d_out;                  // [32,256,64,64]

  ushort* xT   = (ushort*)d_ws;                                   // 71,368,704 B
  ushort* wmod = (ushort*)((char*)d_ws + (size_t)XT_TOTAL_BYTES); // 37,748,736 B

  k_zeroborder<<<256,         256, 0, stream>>>((uint4*)d_ws);
  k_xpose     <<<32 * 64 * 4, 256, 0, stream>>>(x, xT);
  k_modw      <<<32 * 256,    256, 0, stream>>>(W, y, wmod);
  k_gemm      <<<512,         512, 0, stream>>>(wmod, xT, bias, out);
}

// Round 2
// 374.871 us; speedup vs baseline: 1.1197x; 1.0543x over previous
//
#include <hip/hip_runtime.h>
#include <hip/hip_bf16.h>

typedef __attribute__((ext_vector_type(8))) short short8;
typedef __attribute__((ext_vector_type(4))) float f32x4;

#define XT_IMG_BYTES (66*66*256*2)         // 2,230,272 per sample
#define XT_TOTAL_BYTES (32LL*XT_IMG_BYTES) // 71,368,704
#define WM_ROW_BYTES (2304*2)              // 4608
#define WM_IMG_BYTES (256*WM_ROW_BYTES)    // 1,179,648

static __device__ __forceinline__ void async16(void* lds, const void* g) {
  __builtin_amdgcn_global_load_lds((const __attribute__((address_space(1))) void*)g,
                                   (__attribute__((address_space(3))) void*)lds, 16, 0, 0);
}
static __device__ __forceinline__ ushort f2bf(float f) {
  __hip_bfloat16 h = __float2bfloat16(f);
  return *reinterpret_cast<ushort*>(&h);
}

// ---------------- fused prep: xpose (0..8191) | modw (8192..16383) | border ----
__global__ __launch_bounds__(256) void k_prep(const float* __restrict__ x,
                                              const float* __restrict__ W,
                                              const float* __restrict__ y,
                                              ushort* __restrict__ xT,
                                              ushort* __restrict__ wmod) {
  __shared__ float smem[64][65];
  const int bid = blockIdx.x;
  const int t   = threadIdx.x;

  if (bid < 8192) {
    // ---- x [b][c][h][w] fp32 -> xT [b][h+1][w+1][c] bf16 (interior)
    const int b  = bid >> 8;
    const int h  = (bid >> 2) & 63;
    const int c0 = (bid & 3) << 6;
    const int tw = t & 63, tg = t >> 6;
    const float* xp = x + (size_t)(b * 256 + c0) * 4096 + h * 64 + tw;
#pragma unroll
    for (int j = 0; j < 16; ++j) {
      int il = j * 4 + tg;
      smem[il][tw] = xp[(size_t)il * 4096];
    }
    __syncthreads();
    const int q  = t & 7;    // channel octet
    const int w0 = t >> 3;   // 0..31
    ushort* op = xT + (size_t)b * (66 * 66 * 256) + ((size_t)(h + 1) * 66 + 1) * 256 + c0;
#pragma unroll
    for (int j = 0; j < 2; ++j) {
      const int wl = j * 32 + w0;
      short8 v;
#pragma unroll
      for (int k2 = 0; k2 < 8; ++k2) v[k2] = (short)f2bf(smem[8 * q + k2][wl]);
      *(short8*)(op + (size_t)wl * 256 + 8 * q) = v;  // 16B stores
    }
  } else if (bid < 16384) {
    // ---- modulate+demodulate weights -> wmod[b][o][r*256+i] bf16
    float* red = &smem[0][0];
    const int bb = bid - 8192;
    const int b = bb >> 8, o = bb & 255;
    const float* wp = W + (size_t)(o * 256 + t) * 9;
    float wr[9];
#pragma unroll
    for (int r = 0; r < 9; ++r) wr[r] = wp[r];
    const float ym = y[b * 256 + t] + 1.0f;
    float ss = 0.f;
#pragma unroll
    for (int r = 0; r < 9; ++r) ss += wr[r] * wr[r];
    red[t] = ss * ym * ym;
    __syncthreads();
    for (int s = 128; s > 0; s >>= 1) {
      if (t < s) red[t] += red[t + s];
      __syncthreads();
    }
    const float sc = rsqrtf(red[0] + 1e-8f) * ym;
    ushort* op = wmod + (size_t)(b * 256 + o) * 2304 + t;
#pragma unroll
    for (int r = 0; r < 9; ++r) op[r * 256] = f2bf(wr[r] * sc);
  } else {
    // ---- zero the pad border of xT
    const int zb = bid - 16384;            // 0..255
    const int b  = zb >> 3;
    const int tt = ((zb & 7) << 8) | t;    // 0..2047
    uint4* xT4 = (uint4*)xT;
    const uint4 z = make_uint4(0u, 0u, 0u, 0u);
    uint4* base = xT4 + (size_t)b * (66 * 66 * 32);
    uint4* r0  = base;
    uint4* r65 = base + (size_t)65 * 66 * 32;
    for (int i = tt; i < 2112; i += 2048) { r0[i] = z; r65[i] = z; }
    {
      int r = (tt >> 5) + 1, c = tt & 31;
      base[((size_t)r * 66 + 0)  * 32 + c] = z;
      base[((size_t)r * 66 + 65) * 32 + c] = z;
    }
  }
}

// ---------------- implicit-GEMM conv, 256x256 tile, BK=64, 8 waves --------------
// 4-phase-per-K-tile schedule (m201 template): each phase = {ds_read subtile,
// stage-issue, s_barrier, 16 MFMA, s_barrier}. Counted vmcnt once per tile (P3).
// LDS rows XOR-swizzled at 16B granule (g ^= row&7) via pre-swizzled global src.
__global__ __launch_bounds__(512, 2) void k_gemm(const ushort* __restrict__ wmod,
                                                 const ushort* __restrict__ xT,
                                                 const float* __restrict__ bias,
                                                 float* __restrict__ out) {
  __shared__ ushort ldsA[2][16384];  // [buf][row o 0..255][k 0..63] (swizzled)
  __shared__ ushort ldsB[2][16384];  // [buf][pixel 0..255][k 0..63] (swizzled)

  const int t  = threadIdx.x;
  const int bx = blockIdx.x;
  const int xcd = bx & 7;                   // hw round-robins blocks over XCDs
  const int idx = bx >> 3;                  // 0..63
  const int b   = xcd + ((idx >> 4) << 3);  // 4 samples per XCD
  const int tn  = idx & 15;                 // N-tile: 4 image rows
  const int n0  = tn << 8;
  const int h0  = tn << 2;

  const int ln = t & 15;          // lane&15 -> fragment row/col
  const int kq = (t >> 4) & 3;    // lane>>4 -> k-granule
  const int wv = t >> 6;
  const int wm = wv >> 2;         // 0..1  (128 output rows each)
  const int wn = wv & 3;          // 0..3  (64 output cols each)

  const char* wmodB = (const char*)wmod + (size_t)b * WM_IMG_BYTES;
  const char* xTB   = (const char*)xT   + (size_t)b * XT_IMG_BYTES;

  // per-thread staging source offsets (bytes), granule pre-swizzled g^(row&7)
  int gAoff[4], gBoff[4];
#pragma unroll
  for (int j = 0; j < 4; ++j) {
    const int s = j * 512 + t;          // slot 0..2047
    const int row = s >> 3, g = s & 7;
    gAoff[j] = row * WM_ROW_BYTES + ((g ^ (row & 7)) << 4);
    const int hr = row >> 6, wc = row & 63;  // B: row == pixel index
    gBoff[j] = ((h0 + hr) * 66 + wc) * 512 + ((g ^ (row & 7)) << 4);
  }

  // LDS read bases (ushort units)
  const int swz = ln & 7;
  const int g0 = ((0 | kq) ^ swz) << 3;   // khalf 0 granule
  const int g1 = ((4 | kq) ^ swz) << 3;   // khalf 1 granule
  const int aBase = (wm * 128 + ln) * 64;
  const int bBase = (wn * 64  + ln) * 64;

  f32x4 acc[8][4];
  const f32x4 z4 = {0.f, 0.f, 0.f, 0.f};
#pragma unroll
  for (int i = 0; i < 8; ++i)
#pragma unroll
    for (int j = 0; j < 4; ++j) acc[i][j] = z4;

#define STAGE_A(KO, BUF) do {                                        \
    ushort* la_ = &ldsA[BUF][0];                                     \
    async16(la_ + (0 * 512 + t) * 8, wmodB + gAoff[0] + (KO));       \
    async16(la_ + (1 * 512 + t) * 8, wmodB + gAoff[1] + (KO));       \
    async16(la_ + (2 * 512 + t) * 8, wmodB + gAoff[2] + (KO));       \
    async16(la_ + (3 * 512 + t) * 8, wmodB + gAoff[3] + (KO));       \
  } while (0)
#define STAGE_B(KO, BUF) do {                                        \
    ushort* lb_ = &ldsB[BUF][0];                                     \
    async16(lb_ + (0 * 512 + t) * 8, xTB + gBoff[0] + (KO));         \
    async16(lb_ + (1 * 512 + t) * 8, xTB + gBoff[1] + (KO));         \
    async16(lb_ + (2 * 512 + t) * 8, xTB + gBoff[2] + (KO));         \
    async16(lb_ + (3 * 512 + t) * 8, xTB + gBoff[3] + (KO));         \
  } while (0)

#define MF(F, E, A, B) acc[F][E] = __builtin_amdgcn_mfma_f32_16x16x32_bf16(A, B, acc[F][E], 0, 0, 0)
#define FENCE() __builtin_amdgcn_sched_barrier(0)
#define BAR()   __builtin_amdgcn_s_barrier()

  // prologue: stage tile 0 into buf 0
  STAGE_A(0, 0);
  STAGE_B(0, 0);
  asm volatile("s_waitcnt vmcnt(0)" ::: "memory");
  BAR();

  int cur = 0;
#pragma unroll 1
  for (int kt = 0; kt < 36; ++kt) {
    const int nk  = kt + 1;
    const int r_  = nk >> 2;
    const int c2_ = (nk & 3) << 7;
    const int kh_ = r_ / 3;
    const int kw_ = r_ - kh_ * 3;
    const int koA = r_ * 512 + c2_;
    const int koB = (kh_ * 66 + kw_) * 512 + c2_;
    const ushort* bufA = &ldsA[cur][0];
    const ushort* bufB = &ldsB[cur][0];
    const int nb = cur ^ 1;

    // ---------------- P0: rows 0-3, khalf 0 ----------------
    short8 A0 = *(const short8*)(bufA + aBase + 0 * 1024 + g0);
    short8 A1 = *(const short8*)(bufA + aBase + 1 * 1024 + g0);
    short8 A2 = *(const short8*)(bufA + aBase + 2 * 1024 + g0);
    short8 A3 = *(const short8*)(bufA + aBase + 3 * 1024 + g0);
    short8 B0 = *(const short8*)(bufB + bBase + 0 * 1024 + g0);
    short8 B1 = *(const short8*)(bufB + bBase + 1 * 1024 + g0);
    short8 B2 = *(const short8*)(bufB + bBase + 2 * 1024 + g0);
    short8 B3 = *(const short8*)(bufB + bBase + 3 * 1024 + g0);
    if (kt < 35) STAGE_A(koA, nb);
    FENCE(); BAR(); FENCE();
    __builtin_amdgcn_s_setprio(1);
    MF(0,0,A0,B0); MF(1,0,A1,B0); MF(2,0,A2,B0); MF(3,0,A3,B0);
    MF(0,1,A0,B1); MF(1,1,A1,B1); MF(2,1,A2,B1); MF(3,1,A3,B1);
    MF(0,2,A0,B2); MF(1,2,A1,B2); MF(2,2,A2,B2); MF(3,2,A3,B2);
    MF(0,3,A0,B3); MF(1,3,A1,B3); MF(2,3,A2,B3); MF(3,3,A3,B3);
    __builtin_amdgcn_s_setprio(0);
    FENCE(); BAR();

    // ---------------- P1: rows 4-7, khalf 0 (reuse B0-3) ----------------
    short8 A4 = *(const short8*)(bufA + aBase + 4 * 1024 + g0);
    short8 A5 = *(const short8*)(bufA + aBase + 5 * 1024 + g0);
    short8 A6 = *(const short8*)(bufA + aBase + 6 * 1024 + g0);
    short8 A7 = *(const short8*)(bufA + aBase + 7 * 1024 + g0);
    if (kt < 35) STAGE_B(koB, nb);
    FENCE(); BAR(); FENCE();
    __builtin_amdgcn_s_setprio(1);
    MF(4,0,A4,B0); MF(5,0,A5,B0); MF(6,0,A6,B0); MF(7,0,A7,B0);
    MF(4,1,A4,B1); MF(5,1,A5,B1); MF(6,1,A6,B1); MF(7,1,A7,B1);
    MF(4,2,A4,B2); MF(5,2,A5,B2); MF(6,2,A6,B2); MF(7,2,A7,B2);
    MF(4,3,A4,B3); MF(5,3,A5,B3); MF(6,3,A6,B3); MF(7,3,A7,B3);
    __builtin_amdgcn_s_setprio(0);
    FENCE(); BAR();

    // ---------------- P2: rows 0-3, khalf 1 ----------------
    short8 C0 = *(const short8*)(bufA + aBase + 0 * 1024 + g1);
    short8 C1 = *(const short8*)(bufA + aBase + 1 * 1024 + g1);
    short8 C2 = *(const short8*)(bufA + aBase + 2 * 1024 + g1);
    short8 C3 = *(const short8*)(bufA + aBase + 3 * 1024 + g1);
    short8 D0 = *(const short8*)(bufB + bBase + 0 * 1024 + g1);
    short8 D1 = *(const short8*)(bufB + bBase + 1 * 1024 + g1);
    short8 D2 = *(const short8*)(bufB + bBase + 2 * 1024 + g1);
    short8 D3 = *(const short8*)(bufB + bBase + 3 * 1024 + g1);
    FENCE(); BAR(); FENCE();
    __builtin_amdgcn_s_setprio(1);
    MF(0,0,C0,D0); MF(1,0,C1,D0); MF(2,0,C2,D0); MF(3,0,C3,D0);
    MF(0,1,C0,D1); MF(1,1,C1,D1); MF(2,1,C2,D1); MF(3,1,C3,D1);
    MF(0,2,C0,D2); MF(1,2,C1,D2); MF(2,2,C2,D2); MF(3,2,C3,D2);
    MF(0,3,C0,D3); MF(1,3,C1,D3); MF(2,3,C2,D3); MF(3,3,C3,D3);
    __builtin_amdgcn_s_setprio(0);
    FENCE(); BAR();

    // ---------------- P3: rows 4-7, khalf 1 ----------------
    short8 C4 = *(const short8*)(bufA + aBase + 4 * 1024 + g1);
    short8 C5 = *(const short8*)(bufA + aBase + 5 * 1024 + g1);
    short8 C6 = *(const short8*)(bufA + aBase + 6 * 1024 + g1);
    short8 C7 = *(const short8*)(bufA + aBase + 7 * 1024 + g1);
    asm volatile("s_waitcnt vmcnt(0)" ::: "memory");  // next tile's 8 loads landed
    FENCE(); BAR(); FENCE();
    __builtin_amdgcn_s_setprio(1);
    MF(4,0,C4,D0); MF(5,0,C5,D0); MF(6,0,C6,D0); MF(7,0,C7,D0);
    MF(4,1,C4,D1); MF(5,1,C5,D1); MF(6,1,C6,D1); MF(7,1,C7,D1);
    MF(4,2,C4,D2); MF(5,2,C5,D2); MF(6,2,C6,D2); MF(7,2,C7,D2);
    MF(4,3,C4,D3); MF(5,3,C5,D3); MF(6,3,C6,D3); MF(7,3,C7,D3);
    __builtin_amdgcn_s_setprio(0);
    FENCE(); BAR();

    cur = nb;
  }

  // epilogue: C row = o (row=(lane>>4)*4+reg), col = n (lane&15)
  const float* bp = bias + wm * 128;
  float* outB = out + ((size_t)(b * 256 + wm * 128)) * 4096 + n0 + wn * 64 + ln;
#pragma unroll
  for (int mi = 0; mi < 8; ++mi) {
#pragma unroll
    for (int rg = 0; rg < 4; ++rg) {
      const int orow = mi * 16 + kq * 4 + rg;
      const float bv = bp[orow];
      float* po = outB + (size_t)orow * 4096;
#pragma unroll
      for (int ni = 0; ni < 4; ++ni) po[ni * 16] = acc[mi][ni][rg] + bv;
    }
  }
#undef STAGE_A
#undef STAGE_B
#undef MF
#undef FENCE
#undef BAR
}

extern "C" void kernel_launch(void* const* d_in, const int* in_sizes, int n_in,
                              void* d_out, int out_size, void* d_ws, size_t ws_size,
                              hipStream_t stream) {
  const float* x    = (const float*)d_in[0];   // [32,256,64,64]
  const float* y    = (const float*)d_in[1];   // [32,256]
  const float* W    = (const float*)d_in[2];   // [256,256,3,3]
  const float* bias = (const float*)d_in[3];   // [256]
  float* out = (float*)d_out;                  // [32,256,64,64]

  ushort* xT   = (ushort*)d_ws;                                   // 71,368,704 B
  ushort* wmod = (ushort*)((char*)d_ws + (size_t)XT_TOTAL_BYTES); // 37,748,736 B

  k_prep<<<16640, 256, 0, stream>>>(x, W, y, xT, wmod);
  k_gemm<<<512,   512, 0, stream>>>(wmod, xT, bias, out);
}

// Round 3
// 373.759 us; speedup vs baseline: 1.1230x; 1.0030x over previous
//
#include <hip/hip_runtime.h>
#include <hip/hip_bf16.h>

typedef __attribute__((ext_vector_type(8))) short short8;
typedef __attribute__((ext_vector_type(4))) float f32x4;

#define XT_IMG_BYTES (66*66*256*2)         // 2,230,272 per sample
#define XT_TOTAL_BYTES (32LL*XT_IMG_BYTES) // 71,368,704
#define WM_ROW_BYTES (2304*2)              // 4608
#define WM_IMG_BYTES (256*WM_ROW_BYTES)    // 1,179,648

static __device__ __forceinline__ void async16(void* lds, const void* g) {
  __builtin_amdgcn_global_load_lds((const __attribute__((address_space(1))) void*)g,
                                   (__attribute__((address_space(3))) void*)lds, 16, 0, 0);
}
static __device__ __forceinline__ ushort f2bf(float f) {
  __hip_bfloat16 h = __float2bfloat16(f);
  return *reinterpret_cast<ushort*>(&h);
}

// ---------------- fused prep: xpose (0..8191) | modw (8192..16383) | border ----
__global__ __launch_bounds__(256) void k_prep(const float* __restrict__ x,
                                              const float* __restrict__ W,
                                              const float* __restrict__ y,
                                              ushort* __restrict__ xT,
                                              ushort* __restrict__ wmod) {
  __shared__ float smem[64][65];
  const int bid = blockIdx.x;
  const int t   = threadIdx.x;

  if (bid < 8192) {
    // ---- x [b][c][h][w] fp32 -> xT [b][h+1][w+1][c] bf16 (interior)
    const int b  = bid >> 8;
    const int h  = (bid >> 2) & 63;
    const int c0 = (bid & 3) << 6;
    const int tw = t & 63, tg = t >> 6;
    const float* xp = x + (size_t)(b * 256 + c0) * 4096 + h * 64 + tw;
#pragma unroll
    for (int j = 0; j < 16; ++j) {
      int il = j * 4 + tg;
      smem[il][tw] = xp[(size_t)il * 4096];
    }
    __syncthreads();
    const int q  = t & 7;    // channel octet
    const int w0 = t >> 3;   // 0..31
    ushort* op = xT + (size_t)b * (66 * 66 * 256) + ((size_t)(h + 1) * 66 + 1) * 256 + c0;
#pragma unroll
    for (int j = 0; j < 2; ++j) {
      const int wl = j * 32 + w0;
      short8 v;
#pragma unroll
      for (int k2 = 0; k2 < 8; ++k2) v[k2] = (short)f2bf(smem[8 * q + k2][wl]);
      *(short8*)(op + (size_t)wl * 256 + 8 * q) = v;  // 16B stores
    }
  } else if (bid < 16384) {
    // ---- modulate+demodulate weights -> wmod[b][o][r*256+i] bf16
    float* red = &smem[0][0];
    const int bb = bid - 8192;
    const int b = bb >> 8, o = bb & 255;
    const float* wp = W + (size_t)(o * 256 + t) * 9;
    float wr[9];
#pragma unroll
    for (int r = 0; r < 9; ++r) wr[r] = wp[r];
    const float ym = y[b * 256 + t] + 1.0f;
    float ss = 0.f;
#pragma unroll
    for (int r = 0; r < 9; ++r) ss += wr[r] * wr[r];
    red[t] = ss * ym * ym;
    __syncthreads();
    for (int s = 128; s > 0; s >>= 1) {
      if (t < s) red[t] += red[t + s];
      __syncthreads();
    }
    const float sc = rsqrtf(red[0] + 1e-8f) * ym;
    ushort* op = wmod + (size_t)(b * 256 + o) * 2304 + t;
#pragma unroll
    for (int r = 0; r < 9; ++r) op[r * 256] = f2bf(wr[r] * sc);
  } else {
    // ---- zero the pad border of xT
    const int zb = bid - 16384;            // 0..255
    const int b  = zb >> 3;
    const int tt = ((zb & 7) << 8) | t;    // 0..2047
    uint4* xT4 = (uint4*)xT;
    const uint4 z = make_uint4(0u, 0u, 0u, 0u);
    uint4* base = xT4 + (size_t)b * (66 * 66 * 32);
    uint4* r0  = base;
    uint4* r65 = base + (size_t)65 * 66 * 32;
    for (int i = tt; i < 2112; i += 2048) { r0[i] = z; r65[i] = z; }
    {
      int r = (tt >> 5) + 1, c = tt & 31;
      base[((size_t)r * 66 + 0)  * 32 + c] = z;
      base[((size_t)r * 66 + 65) * 32 + c] = z;
    }
  }
}

// ---------------- implicit-GEMM conv, 256x256 tile, BK=64, 8 waves --------------
// 2 barriers per K-tile (slab-lifetime analysis: A-slabs 0,2 + all B last read in
// P2 -> stage kt+2's 6 loads during P3; A-slabs 1,3 last read in P3 -> kt+1's
// remaining 2 loads issue at next tile's P0). Counted vmcnt(6) in steady state --
// the 8 loads of the tile about to be consumed were issued >=4 phases earlier.
// LDS rows XOR-swizzled at 16B granule (g ^= row&7) via pre-swizzled global src.
__global__ __launch_bounds__(512, 2) void k_gemm(const ushort* __restrict__ wmod,
                                                 const ushort* __restrict__ xT,
                                                 const float* __restrict__ bias,
                                                 float* __restrict__ out) {
  __shared__ ushort ldsA[2][16384];  // [buf][row o 0..255][k 0..63] (swizzled)
  __shared__ ushort ldsB[2][16384];  // [buf][pixel 0..255][k 0..63] (swizzled)

  const int t  = threadIdx.x;
  const int bx = blockIdx.x;
  const int xcd = bx & 7;                   // hw round-robins blocks over XCDs
  const int idx = bx >> 3;                  // 0..63
  const int b   = xcd + ((idx >> 4) << 3);  // 4 samples per XCD
  const int tn  = idx & 15;                 // N-tile: 4 image rows
  const int n0  = tn << 8;
  const int h0  = tn << 2;

  const int ln = t & 15;          // lane&15 -> fragment row/col
  const int kq = (t >> 4) & 3;    // lane>>4 -> k-granule
  const int wv = t >> 6;
  const int wm = wv >> 2;         // 0..1  (128 output rows each)
  const int wn = wv & 3;          // 0..3  (64 output cols each)

  const char* wmodB = (const char*)wmod + (size_t)b * WM_IMG_BYTES;
  const char* xTB   = (const char*)xT   + (size_t)b * XT_IMG_BYTES;

  // per-thread staging source offsets (bytes), granule pre-swizzled g^(row&7)
  int gAoff[4], gBoff[4];
#pragma unroll
  for (int j = 0; j < 4; ++j) {
    const int s = j * 512 + t;          // slot 0..2047
    const int row = s >> 3, g = s & 7;
    gAoff[j] = row * WM_ROW_BYTES + ((g ^ (row & 7)) << 4);
    const int hr = row >> 6, wc = row & 63;  // B: row == pixel index
    gBoff[j] = ((h0 + hr) * 66 + wc) * 512 + ((g ^ (row & 7)) << 4);
  }

  // LDS read bases (ushort units)
  const int swz = ln & 7;
  const int g0 = ((0 | kq) ^ swz) << 3;   // khalf 0 granule
  const int g1 = ((4 | kq) ^ swz) << 3;   // khalf 1 granule
  const int aBase = (wm * 128 + ln) * 64;
  const int bBase = (wn * 64  + ln) * 64;

  f32x4 acc[8][4];
  const f32x4 z4 = {0.f, 0.f, 0.f, 0.f};
#pragma unroll
  for (int i = 0; i < 8; ++i)
#pragma unroll
    for (int j = 0; j < 4; ++j) acc[i][j] = z4;

  // slab j of A covers rows 64j..64j+63; same for B (pixel rows)
#define LOAD_A(J, KO, BUF) async16(&ldsA[BUF][0] + ((J) * 512 + t) * 8, wmodB + gAoff[J] + (KO))
#define LOAD_B(J, KO, BUF) async16(&ldsB[BUF][0] + ((J) * 512 + t) * 8, xTB   + gBoff[J] + (KO))

#define MF(F, E, A, B) acc[F][E] = __builtin_amdgcn_mfma_f32_16x16x32_bf16(A, B, acc[F][E], 0, 0, 0)
#define FENCE() __builtin_amdgcn_sched_barrier(0)
#define BAR()   __builtin_amdgcn_s_barrier()

  // ---- prologue: full tile0 -> buf0 (8 loads), tile1's A0,A2,B0-3 -> buf1 (6)
  LOAD_A(0, 0, 0); LOAD_A(1, 0, 0); LOAD_A(2, 0, 0); LOAD_A(3, 0, 0);
  LOAD_B(0, 0, 0); LOAD_B(1, 0, 0); LOAD_B(2, 0, 0); LOAD_B(3, 0, 0);
  {
    const int koA1 = 0 * 512 + 128;           // tile 1: r=0, ch-offset 64
    const int koB1 = (0 * 66 + 0) * 512 + 128;
    LOAD_A(0, koA1, 1); LOAD_A(2, koA1, 1);
    LOAD_B(0, koB1, 1); LOAD_B(1, koB1, 1); LOAD_B(2, koB1, 1); LOAD_B(3, koB1, 1);
  }
  asm volatile("s_waitcnt vmcnt(6)" ::: "memory");  // tile0's 8 landed; tile1's fly
  FENCE(); BAR(); FENCE();

#pragma unroll 1
  for (int kt = 0; kt < 36; ++kt) {
    const int cur = kt & 1, nb = cur ^ 1;
    const ushort* bufA = &ldsA[cur][0];
    const ushort* bufB = &ldsB[cur][0];

    // offsets for tile kt+1 (A slabs 1,3 -> buf nb) and kt+2 (A0,A2,B -> buf cur)
    const int n1 = kt + 1;
    const int koA1 = (n1 >> 2) * 512 + ((n1 & 3) << 7);
    const int n2 = kt + 2;
    const int r2 = n2 >> 2;
    const int kh2 = r2 / 3, kw2 = r2 - kh2 * 3;
    const int koA2 = r2 * 512 + ((n2 & 3) << 7);
    const int koB2 = (kh2 * 66 + kw2) * 512 + ((n2 & 3) << 7);

    // ---------------- P0: A rows wm*128+0..63 khalf0, B all khalf0 --------------
    short8 A0 = *(const short8*)(bufA + aBase + 0 * 1024 + g0);
    short8 A1 = *(const short8*)(bufA + aBase + 1 * 1024 + g0);
    short8 A2 = *(const short8*)(bufA + aBase + 2 * 1024 + g0);
    short8 A3 = *(const short8*)(bufA + aBase + 3 * 1024 + g0);
    short8 B0 = *(const short8*)(bufB + bBase + 0 * 1024 + g0);
    short8 B1 = *(const short8*)(bufB + bBase + 1 * 1024 + g0);
    short8 B2 = *(const short8*)(bufB + bBase + 2 * 1024 + g0);
    short8 B3 = *(const short8*)(bufB + bBase + 3 * 1024 + g0);
    if (kt < 35) { LOAD_A(1, koA1, nb); LOAD_A(3, koA1, nb); }  // kt+1's A1,A3
    __builtin_amdgcn_s_setprio(1);
    MF(0,0,A0,B0); MF(1,0,A1,B0); MF(2,0,A2,B0); MF(3,0,A3,B0);
    MF(0,1,A0,B1); MF(1,1,A1,B1); MF(2,1,A2,B1); MF(3,1,A3,B1);
    MF(0,2,A0,B2); MF(1,2,A1,B2); MF(2,2,A2,B2); MF(3,2,A3,B2);
    MF(0,3,A0,B3); MF(1,3,A1,B3); MF(2,3,A2,B3); MF(3,3,A3,B3);
    __builtin_amdgcn_s_setprio(0);

    // ---------------- P1: A rows wm*128+64..127 khalf0 (reuse B0-3) -------------
    short8 A4 = *(const short8*)(bufA + aBase + 4 * 1024 + g0);
    short8 A5 = *(const short8*)(bufA + aBase + 5 * 1024 + g0);
    short8 A6 = *(const short8*)(bufA + aBase + 6 * 1024 + g0);
    short8 A7 = *(const short8*)(bufA + aBase + 7 * 1024 + g0);
    __builtin_amdgcn_s_setprio(1);
    MF(4,0,A4,B0); MF(5,0,A5,B0); MF(6,0,A6,B0); MF(7,0,A7,B0);
    MF(4,1,A4,B1); MF(5,1,A5,B1); MF(6,1,A6,B1); MF(7,1,A7,B1);
    MF(4,2,A4,B2); MF(5,2,A5,B2); MF(6,2,A6,B2); MF(7,2,A7,B2);
    MF(4,3,A4,B3); MF(5,3,A5,B3); MF(6,3,A6,B3); MF(7,3,A7,B3);
    __builtin_amdgcn_s_setprio(0);
    FENCE();  // cap register live-range of P0/P1 fragments

    // ---------------- P2: A rows 0..63 khalf1, B all khalf1 ---------------------
    short8 C0 = *(const short8*)(bufA + aBase + 0 * 1024 + g1);
    short8 C1 = *(const short8*)(bufA + aBase + 1 * 1024 + g1);
    short8 C2 = *(const short8*)(bufA + aBase + 2 * 1024 + g1);
    short8 C3 = *(const short8*)(bufA + aBase + 3 * 1024 + g1);
    short8 D0 = *(const short8*)(bufB + bBase + 0 * 1024 + g1);
    short8 D1 = *(const short8*)(bufB + bBase + 1 * 1024 + g1);
    short8 D2 = *(const short8*)(bufB + bBase + 2 * 1024 + g1);
    short8 D3 = *(const short8*)(bufB + bBase + 3 * 1024 + g1);
    __builtin_amdgcn_s_setprio(1);
    MF(0,0,C0,D0); MF(1,0,C1,D0); MF(2,0,C2,D0); MF(3,0,C3,D0);
    MF(0,1,C0,D1); MF(1,1,C1,D1); MF(2,1,C2,D1); MF(3,1,C3,D1);
    MF(0,2,C0,D2); MF(1,2,C1,D2); MF(2,2,C2,D2); MF(3,2,C3,D2);
    MF(0,3,C0,D3); MF(1,3,C1,D3); MF(2,3,C2,D3); MF(3,3,C3,D3);
    __builtin_amdgcn_s_setprio(0);

    FENCE(); BAR(); FENCE();   // all waves done with A0,A2 + B slabs of buf cur

    // ---------------- P3: A rows 64..127 khalf1; stage kt+2's 6 into buf cur ----
    short8 C4 = *(const short8*)(bufA + aBase + 4 * 1024 + g1);
    short8 C5 = *(const short8*)(bufA + aBase + 5 * 1024 + g1);
    short8 C6 = *(const short8*)(bufA + aBase + 6 * 1024 + g1);
    short8 C7 = *(const short8*)(bufA + aBase + 7 * 1024 + g1);
    if (kt < 34) {
      LOAD_A(0, koA2, cur); LOAD_A(2, koA2, cur);
      LOAD_B(0, koB2, cur); LOAD_B(1, koB2, cur);
      LOAD_B(2, koB2, cur); LOAD_B(3, koB2, cur);
    }
    __builtin_amdgcn_s_setprio(1);
    MF(4,0,C4,D0); MF(5,0,C5,D0); MF(6,0,C6,D0); MF(7,0,C7,D0);
    MF(4,1,C4,D1); MF(5,1,C5,D1); MF(6,1,C6,D1); MF(7,1,C7,D1);
    MF(4,2,C4,D2); MF(5,2,C5,D2); MF(6,2,C6,D2); MF(7,2,C7,D2);
    MF(4,3,C4,D3); MF(5,3,C5,D3); MF(6,3,C6,D3); MF(7,3,C7,D3);
    __builtin_amdgcn_s_setprio(0);

    if (kt < 34) {
      asm volatile("s_waitcnt vmcnt(6)" ::: "memory");  // kt+1's 8 landed
    } else {
      asm volatile("s_waitcnt vmcnt(0)" ::: "memory");  // tail drain
    }
    FENCE(); BAR(); FENCE();   // buf nb ready; A1,A3 of buf cur free for re-stage
  }

  // epilogue: C row = o (row=(lane>>4)*4+reg), col = n (lane&15)
  const float* bp = bias + wm * 128;
  float* outB = out + ((size_t)(b * 256 + wm * 128)) * 4096 + n0 + wn * 64 + ln;
#pragma unroll
  for (int mi = 0; mi < 8; ++mi) {
#pragma unroll
    for (int rg = 0; rg < 4; ++rg) {
      const int orow = mi * 16 + kq * 4 + rg;
      const float bv = bp[orow];
      float* po = outB + (size_t)orow * 4096;
#pragma unroll
      for (int ni = 0; ni < 4; ++ni) po[ni * 16] = acc[mi][ni][rg] + bv;
    }
  }
#undef LOAD_A
#undef LOAD_B
#undef MF
#undef FENCE
#undef BAR
}

extern "C" void kernel_launch(void* const* d_in, const int* in_sizes, int n_in,
                              void* d_out, int out_size, void* d_ws, size_t ws_size,
                              hipStream_t stream) {
  const float* x    = (const float*)d_in[0];   // [32,256,64,64]
  const float* y    = (const float*)d_in[1];   // [32,256]
  const float* W    = (const float*)d_in[2];   // [256,256,3,3]
  const float* bias = (const float*)d_in[3];   // [256]
  float* out = (float*)d_out;                  // [32,256,64,64]

  ushort* xT   = (ushort*)d_ws;                                   // 71,368,704 B
  ushort* wmod = (ushort*)((char*)d_ws + (size_t)XT_TOTAL_BYTES); // 37,748,736 B

  k_prep<<<16640, 256, 0, stream>>>(x, W, y, xT, wmod);
  k_gemm<<<512,   512, 0, stream>>>(wmod, xT, bias, out);
}